// Round 7
// baseline (514.785 us; speedup 1.0000x reference)
//
#include <hip/hip_runtime.h>
#include <math.h>

// ---------------------------------------------------------------------------
// xLSTM decoder block, MI355X gfx950.
// Pipeline (all flat (b*12+ch)*1024+l layout):
//  prep:  weights -> bf16 (Wg/upl/upr/down transposed to [n][k])
//  ln1:   x -> xn (fp32)  [skip]     (Round-7: frontend fusion reverted — it
//  fc:    xn -> xc, x1 (fp32)         cost +22us vs the 3-kernel chain)
//  ln2:   x1 -> xn2 (bf16)
//  gemm0: xn2 @ WgT + bg -> gx (bf16, 6144x4096)
//  rec:   MFMA sLSTM per (head, 16 batches): R^T in VGPR B-fragments
//  upgate:FUSED hn @ [upl|upr] + gelu(left)*right -> glr (bf16, 6144x1024)
//         (left/right tiles in one block; gate kernel + lr traffic gone)
//  gemm2: glr @ WdT + down_b ; epilogue y = silu(xc)*(acc+b+x1)+xn -> yb bf16
//  tail:  FUSED conv1+gelu+LN(len)+conv2+skip. Round-7 v4: thread owns
//         ADJACENT positions (2t,2t+1) -> ds_read_b32 pair loads (was 6x
//         ds_read_u16), ci-outer conv loops, LN folded into conv2 reads.
//         LDS-pipe ops cut ~2.2x (tail was LDS-paced at 100us).
// ---------------------------------------------------------------------------

typedef short short8_t __attribute__((ext_vector_type(8)));
typedef float floatx4 __attribute__((ext_vector_type(4)));
typedef float float2_t __attribute__((ext_vector_type(2)));

typedef unsigned int u32;
typedef const __attribute__((address_space(1))) u32 gu32;
typedef __attribute__((address_space(3))) u32 lu32;

static __device__ __forceinline__ float b2f(unsigned short u) {
    unsigned v = ((unsigned)u) << 16;
    return __builtin_bit_cast(float, v);
}
static __device__ __forceinline__ unsigned short f2b(float f) {
    unsigned u = __builtin_bit_cast(unsigned, f);
    u += 0x7FFFu + ((u >> 16) & 1u);   // RNE
    return (unsigned short)(u >> 16);
}
static __device__ __forceinline__ float2_t make2u(unsigned u) {
    float2_t r;
    r.x = __builtin_bit_cast(float, u << 16);
    r.y = __builtin_bit_cast(float, u & 0xFFFF0000u);
    return r;
}
static __device__ __forceinline__ float gelu_exact(float x) {
    return 0.5f * x * (1.f + erff(x * 0.70710678118654752f));
}
// tanh-form gelu; max abs err ~3e-3, negligible after LN + 0.02-scale conv2.
static __device__ __forceinline__ float gelu_fast(float x) {
    float u = 0.7978845608f * x * (1.f + 0.044715f * x * x);
    u = fminf(fmaxf(u, -9.f), 9.f);
    float e = __expf(2.f * u);
    float t = (e - 1.f) / (e + 1.f);
    return 0.5f * x * (1.f + t);
}

// --------------------------- weight prep ----------------------------------

__global__ __launch_bounds__(256) void transpose_bf16_k(
    const float* __restrict__ src, unsigned short* __restrict__ dst, int K, int N)
{   // dst[n*K+k] = bf16(src[k*N+n]); grid (N/32, K/32), block 256
    __shared__ unsigned short tl[32][33];
    const int n0 = blockIdx.x * 32, k0 = blockIdx.y * 32;
    const int tx = threadIdx.x & 31, ty = threadIdx.x >> 5;
#pragma unroll
    for (int r = 0; r < 4; r++) {
        int k = ty + r * 8;
        tl[tx][k] = f2b(src[(size_t)(k0 + k) * N + n0 + tx]);
    }
    __syncthreads();
#pragma unroll
    for (int r = 0; r < 4; r++) {
        int n = ty * 4 + r;
        dst[(size_t)(n0 + n) * K + k0 + tx] = tl[n][tx];
    }
}

// ------------------------------ layernorm ----------------------------------

template <int BF16OUT>
__global__ __launch_bounds__(256) void ln_kernel(
    const float* __restrict__ in, const float* __restrict__ g,
    const float* __restrict__ be, void* __restrict__ outp)
{
    const int row = blockIdx.x;
    const float* xr = in + (size_t)row * 1024;
    const int t = threadIdx.x;
    float v[4];
    float s = 0.f, ss = 0.f;
#pragma unroll
    for (int u = 0; u < 4; u++) {
        float q = xr[t + u * 256];
        v[u] = q; s += q; ss += q * q;
    }
#pragma unroll
    for (int off = 32; off >= 1; off >>= 1) {
        s += __shfl_xor(s, off);
        ss += __shfl_xor(ss, off);
    }
    __shared__ float red[8];
    const int wv = t >> 6, la = t & 63;
    if (la == 0) { red[wv] = s; red[4 + wv] = ss; }
    __syncthreads();
    s = red[0] + red[1] + red[2] + red[3];
    ss = red[4] + red[5] + red[6] + red[7];
    float mu = s * (1.f / 1024.f);
    float var = ss * (1.f / 1024.f) - mu * mu;
    float rs = rsqrtf(var + 1e-5f);
#pragma unroll
    for (int u = 0; u < 4; u++) {
        int i = t + u * 256;
        float yv = (v[u] - mu) * rs * g[i] + be[i];
        if (BF16OUT)
            ((unsigned short*)outp)[(size_t)row * 1024 + i] = f2b(yv);
        else
            ((float*)outp)[(size_t)row * 1024 + i] = yv;
    }
}

// ---------------------- fc1 (conv k3) + fc2 (1x1) --------------------------

__global__ __launch_bounds__(256) void fc_kernel(
    const float* __restrict__ xn,
    const float* __restrict__ w1, const float* __restrict__ b1,
    const float* __restrict__ w2, const float* __restrict__ b2,
    float* __restrict__ xc, float* __restrict__ x1)
{
    const int t = threadIdx.x;
    const int gid = blockIdx.x * 256 + t;
    const int b = gid >> 10, l = gid & 1023;
    const float* xb = xn + (size_t)b * 12288;
    float inm[12], in0[12], inp[12];
#pragma unroll
    for (int ci = 0; ci < 12; ci++) {
        in0[ci] = xb[ci * 1024 + l];
        inm[ci] = (l > 0) ? xb[ci * 1024 + l - 1] : 0.f;
        inp[ci] = (l < 1023) ? xb[ci * 1024 + l + 1] : 0.f;
    }
    float xcv[12];
#pragma unroll
    for (int o = 0; o < 12; o++) {
        float a = b1[o];
#pragma unroll
        for (int ci = 0; ci < 12; ci++) {
            const float* wp = w1 + o * 36 + ci * 3;  // uniform -> s_load
            a += inm[ci] * wp[0] + in0[ci] * wp[1] + inp[ci] * wp[2];
        }
        xcv[o] = a;
        xc[(size_t)b * 12288 + o * 1024 + l] = a;
    }
#pragma unroll
    for (int o = 0; o < 12; o++) {
        float a = b2[o];
#pragma unroll
        for (int ci = 0; ci < 12; ci++) a += xcv[ci] * w2[o * 12 + ci];
        x1[(size_t)b * 12288 + o * 1024 + l] = a;
    }
}

// ------------------------------ bf16 GEMM ----------------------------------
// MODE 0: store bf16.  MODE 2: y = silu(xc)*(acc+bias+x1) + skip, store BF16.

template <int MODE>
__global__ __launch_bounds__(256) void gemm_kernel(
    const unsigned short* __restrict__ A, const unsigned short* __restrict__ BT,
    const float* __restrict__ bias, void* __restrict__ out,
    int M, int N, int K,
    const float* __restrict__ xc, const float* __restrict__ x1,
    const float* __restrict__ skip)
{
    __shared__ __align__(16) unsigned short sA[128 * 32];
    __shared__ __align__(16) unsigned short sB[128 * 32];
    const int t = threadIdx.x;
    const int m0 = blockIdx.y * 128;
    const int n0 = blockIdx.x * 128;
    const int w = t >> 6;
    const int lane = t & 63;
    const int wr = (w >> 1) * 64;
    const int wc = (w & 1) * 64;
    const int lrow = lane & 15;
    const int quad = lane >> 4;
    const int row_l = t >> 2;
    const int cs = (t & 3) * 8;

    const unsigned short* gA0 = A + (size_t)(m0 + row_l) * K + cs;
    const unsigned short* gA1 = A + (size_t)(m0 + row_l + 64) * K + cs;
    const unsigned short* gB0 = BT + (size_t)(n0 + row_l) * K + cs;
    const unsigned short* gB1 = BT + (size_t)(n0 + row_l + 64) * K + cs;
    unsigned short* lA0 = sA + w * 512;
    unsigned short* lA1 = sA + 2048 + w * 512;
    unsigned short* lB0 = sB + w * 512;
    unsigned short* lB1 = sB + 2048 + w * 512;

    floatx4 acc[4][4];
#pragma unroll
    for (int i = 0; i < 4; i++)
#pragma unroll
        for (int j = 0; j < 4; j++) acc[i][j] = (floatx4)0.f;

    for (int k0 = 0; k0 < K; k0 += 32) {
        __syncthreads();
        __builtin_amdgcn_global_load_lds((gu32*)(gA0 + k0), (lu32*)lA0, 16, 0, 0);
        __builtin_amdgcn_global_load_lds((gu32*)(gA1 + k0), (lu32*)lA1, 16, 0, 0);
        __builtin_amdgcn_global_load_lds((gu32*)(gB0 + k0), (lu32*)lB0, 16, 0, 0);
        __builtin_amdgcn_global_load_lds((gu32*)(gB1 + k0), (lu32*)lB1, 16, 0, 0);
        __syncthreads();
        short8_t af[4], bfr[4];
#pragma unroll
        for (int i = 0; i < 4; i++) {
            af[i] = *(const short8_t*)(sA + (wr + i * 16 + lrow) * 32 + quad * 8);
            bfr[i] = *(const short8_t*)(sB + (wc + i * 16 + lrow) * 32 + quad * 8);
        }
#pragma unroll
        for (int i = 0; i < 4; i++)
#pragma unroll
            for (int j = 0; j < 4; j++)
                acc[i][j] = __builtin_amdgcn_mfma_f32_16x16x32_bf16(
                    af[i], bfr[j], acc[i][j], 0, 0, 0);
    }

#pragma unroll
    for (int i = 0; i < 4; i++) {
#pragma unroll
        for (int j = 0; j < 4; j++) {
#pragma unroll
            for (int r = 0; r < 4; r++) {
                const int gm = m0 + wr + i * 16 + quad * 4 + r;
                const int gn = n0 + wc + j * 16 + lrow;
                const size_t idx = (size_t)gm * N + gn;
                float v = acc[i][j][r] + bias[gn];
                if (MODE == 0) {
                    ((unsigned short*)out)[idx] = f2b(v);
                } else {
                    float xcv = xc[idx];
                    float sig = xcv / (1.f + __expf(-xcv));
                    ((unsigned short*)out)[idx] =
                        f2b(sig * (v + x1[idx]) + skip[idx]);
                }
            }
        }
    }
}

// -------------- fused up-projection + gate: glr = gelu(l)*r ----------------
// A(6144x1024) @ BT(2048x1024): left rows [0,1024) = upl^T, right = upr^T.
// Block computes matched 128x128 left AND right tiles; epilogue gates.
// grid (8, 48), 256 threads.

__global__ __launch_bounds__(256) void gemm_upgate_kernel(
    const unsigned short* __restrict__ A, const unsigned short* __restrict__ BT,
    const float* __restrict__ lbias, const float* __restrict__ rbias,
    unsigned short* __restrict__ glr, int K)
{
    __shared__ __align__(16) unsigned short sA[128 * 32];
    __shared__ __align__(16) unsigned short sL[128 * 32];
    __shared__ __align__(16) unsigned short sR[128 * 32];
    const int t = threadIdx.x;
    const int m0 = blockIdx.y * 128;
    const int n0 = blockIdx.x * 128;
    const int w = t >> 6;
    const int lane = t & 63;
    const int wr = (w >> 1) * 64;
    const int wc = (w & 1) * 64;
    const int lrow = lane & 15;
    const int quad = lane >> 4;
    const int row_l = t >> 2;
    const int cs = (t & 3) * 8;

    const unsigned short* gA0 = A + (size_t)(m0 + row_l) * K + cs;
    const unsigned short* gA1 = A + (size_t)(m0 + row_l + 64) * K + cs;
    const unsigned short* gL0 = BT + (size_t)(n0 + row_l) * K + cs;
    const unsigned short* gL1 = BT + (size_t)(n0 + row_l + 64) * K + cs;
    const unsigned short* gR0 = BT + (size_t)(1024 + n0 + row_l) * K + cs;
    const unsigned short* gR1 = BT + (size_t)(1024 + n0 + row_l + 64) * K + cs;
    unsigned short* lA0 = sA + w * 512;
    unsigned short* lA1 = sA + 2048 + w * 512;
    unsigned short* lL0 = sL + w * 512;
    unsigned short* lL1 = sL + 2048 + w * 512;
    unsigned short* lR0 = sR + w * 512;
    unsigned short* lR1 = sR + 2048 + w * 512;

    floatx4 accL[4][4], accR[4][4];
#pragma unroll
    for (int i = 0; i < 4; i++)
#pragma unroll
        for (int j = 0; j < 4; j++) { accL[i][j] = (floatx4)0.f; accR[i][j] = (floatx4)0.f; }

    for (int k0 = 0; k0 < K; k0 += 32) {
        __syncthreads();
        __builtin_amdgcn_global_load_lds((gu32*)(gA0 + k0), (lu32*)lA0, 16, 0, 0);
        __builtin_amdgcn_global_load_lds((gu32*)(gA1 + k0), (lu32*)lA1, 16, 0, 0);
        __builtin_amdgcn_global_load_lds((gu32*)(gL0 + k0), (lu32*)lL0, 16, 0, 0);
        __builtin_amdgcn_global_load_lds((gu32*)(gL1 + k0), (lu32*)lL1, 16, 0, 0);
        __builtin_amdgcn_global_load_lds((gu32*)(gR0 + k0), (lu32*)lR0, 16, 0, 0);
        __builtin_amdgcn_global_load_lds((gu32*)(gR1 + k0), (lu32*)lR1, 16, 0, 0);
        __syncthreads();
        short8_t af[4], bl[4], br[4];
#pragma unroll
        for (int i = 0; i < 4; i++) {
            af[i] = *(const short8_t*)(sA + (wr + i * 16 + lrow) * 32 + quad * 8);
            bl[i] = *(const short8_t*)(sL + (wc + i * 16 + lrow) * 32 + quad * 8);
            br[i] = *(const short8_t*)(sR + (wc + i * 16 + lrow) * 32 + quad * 8);
        }
#pragma unroll
        for (int i = 0; i < 4; i++)
#pragma unroll
            for (int j = 0; j < 4; j++) {
                accL[i][j] = __builtin_amdgcn_mfma_f32_16x16x32_bf16(
                    af[i], bl[j], accL[i][j], 0, 0, 0);
                accR[i][j] = __builtin_amdgcn_mfma_f32_16x16x32_bf16(
                    af[i], br[j], accR[i][j], 0, 0, 0);
            }
    }

#pragma unroll
    for (int i = 0; i < 4; i++) {
#pragma unroll
        for (int j = 0; j < 4; j++) {
#pragma unroll
            for (int r = 0; r < 4; r++) {
                const int gm = m0 + wr + i * 16 + quad * 4 + r;
                const int gn = n0 + wc + j * 16 + lrow;
                float lv = accL[i][j][r] + lbias[gn];
                float rv = accR[i][j][r] + rbias[gn];
                glr[(size_t)gm * 1024 + gn] = f2b(gelu_exact(lv) * rv);
            }
        }
    }
}

// ------------------- sLSTM recurrence + GroupNorm (MFMA) -------------------
// grid (NH=8, B/16=32) = 256 blocks (1/CU), block 1024 (16 waves, 4/SIMD).

#define RECP 516   // f32 row stride for sRec (2-way bank aliasing only)
#define HBP  136   // bf16 row stride for sHb

__global__ __launch_bounds__(1024, 4) void slstm_rec_kernel(
    const float* __restrict__ Rg,             // [8][512][128] f32
    const unsigned short* __restrict__ gxb,   // [B][12][4096] bf16
    const float* __restrict__ gn_g, const float* __restrict__ gn_b,
    unsigned short* __restrict__ hnb)         // [B][12][1024] bf16
{
    __shared__ __align__(16) float sRec[16 * RECP];
    __shared__ __align__(16) unsigned short sHb[16 * HBP];
    const int head = blockIdx.x;
    const int b0 = blockIdx.y * 16;
    const int t = threadIdx.x;
    const int w = t >> 6;
    const int lane = t & 63;
    const int quad = lane >> 4;
    const int l16 = lane & 15;

    short8_t Bf[2][4];
    {
        const float* Rh = Rg + (size_t)head * 65536;
#pragma unroll
        for (int jt = 0; jt < 2; jt++)
#pragma unroll
            for (int kk = 0; kk < 4; kk++) {
                const float* src =
                    Rh + (size_t)(w * 32 + jt * 16 + l16) * 128 + kk * 32 + quad * 8;
                short8_t v;
#pragma unroll
                for (int j = 0; j < 8; j++) v[j] = (short)f2b(src[j]);
                Bf[jt][kk] = v;
            }
    }

    for (int i = t; i < 16 * HBP; i += 1024) sHb[i] = 0;

    const int la = lane;
    float c0 = 0.f, n0s = 0.f, m0 = 0.f;
    float c1 = 0.f, n1s = 0.f, m1 = 0.f;
    const float gg0 = gn_g[head * 128 + la];
    const float gg1 = gn_g[head * 128 + la + 64];
    const float gb0 = gn_b[head * 128 + la];
    const float gb1 = gn_b[head * 128 + la + 64];

    __syncthreads();

    for (int step = 0; step < 12; step++) {
        const unsigned short* gp =
            gxb + ((size_t)(b0 + w) * 12 + step) * 4096 + head * 512;
        float gz0 = b2f(gp[la]),       gz1 = b2f(gp[64 + la]);
        float gi0 = b2f(gp[128 + la]), gi1 = b2f(gp[192 + la]);
        float gf0 = b2f(gp[256 + la]), gf1 = b2f(gp[320 + la]);
        float go0 = b2f(gp[384 + la]), go1 = b2f(gp[448 + la]);

        short8_t Af[4];
#pragma unroll
        for (int kk = 0; kk < 4; kk++)
            Af[kk] = *(const short8_t*)(sHb + l16 * HBP + kk * 32 + quad * 8);
        floatx4 D0 = (floatx4)0.f, D1 = (floatx4)0.f;
#pragma unroll
        for (int kk = 0; kk < 4; kk++) {
            D0 = __builtin_amdgcn_mfma_f32_16x16x32_bf16(Af[kk], Bf[0][kk], D0, 0, 0, 0);
            D1 = __builtin_amdgcn_mfma_f32_16x16x32_bf16(Af[kk], Bf[1][kk], D1, 0, 0, 0);
        }
#pragma unroll
        for (int r = 0; r < 4; r++) {
            sRec[(quad * 4 + r) * RECP + w * 32 + l16] = D0[r];
            sRec[(quad * 4 + r) * RECP + w * 32 + 16 + l16] = D1[r];
        }
        __syncthreads();

        const float* rr = sRec + w * RECP;
        float zp0 = gz0 + rr[la],       zp1 = gz1 + rr[64 + la];
        float ip0 = gi0 + rr[128 + la], ip1 = gi1 + rr[192 + la];
        float fp0 = gf0 + rr[256 + la], fp1 = gf1 + rr[320 + la];
        float op0 = go0 + rr[384 + la], op1 = go1 + rr[448 + la];

        float e20 = __expf(2.f * zp0), e21 = __expf(2.f * zp1);
        float z0 = (e20 - 1.f) / (e20 + 1.f), z1 = (e21 - 1.f) / (e21 + 1.f);
        float o0 = 1.f / (1.f + __expf(-op0)), o1 = 1.f / (1.f + __expf(-op1));
        float mn0 = fmaxf(fp0 + m0, ip0), mn1 = fmaxf(fp1 + m1, ip1);
        float ie0 = __expf(ip0 - mn0), ie1 = __expf(ip1 - mn1);
        float fe0 = __expf(fp0 + m0 - mn0), fe1 = __expf(fp1 + m1 - mn1);
        c0 = fe0 * c0 + ie0 * z0;  c1 = fe1 * c1 + ie1 * z1;
        n0s = fe0 * n0s + ie0;     n1s = fe1 * n1s + ie1;
        m0 = mn0;                  m1 = mn1;
        float h0 = o0 * (c0 / n0s), h1 = o1 * (c1 / n1s);

        float s = h0 + h1, ss = h0 * h0 + h1 * h1;
#pragma unroll
        for (int off = 32; off >= 1; off >>= 1) {
            s += __shfl_xor(s, off);
            ss += __shfl_xor(ss, off);
        }
        float mu = s * (1.f / 128.f);
        float var = ss * (1.f / 128.f) - mu * mu;
        float rs = rsqrtf(var + 1e-5f);
        size_t base = ((size_t)(b0 + w) * 12 + step) * 1024 + head * 128;
        hnb[base + la] = f2b((h0 - mu) * rs * gg0 + gb0);
        hnb[base + la + 64] = f2b((h1 - mu) * rs * gg1 + gb1);

        sHb[w * HBP + la] = f2b(h0);
        sHb[w * HBP + la + 64] = f2b(h1);
        __syncthreads();
    }
}

// ---------------- fused tail: conv1+gelu+LN(len)+conv2+skip ----------------
// grid 512 (one block per batch), block 512, 2 blocks/CU (74 KB LDS).
// Thread owns ADJACENT positions (2t, 2t+1): pair accesses are single
// ds_read/write_b32; neighbor taps are 2 ds_read_u16. LN folded into conv2
// reads (tap-position-indexed gains). ci-outer conv loops keep regs ~100.

__global__ __launch_bounds__(512, 4) void tail_fused_kernel(
    const unsigned short* __restrict__ y, const float* __restrict__ skip,
    const float* __restrict__ w1, const float* __restrict__ b1,
    const float* __restrict__ w2, const float* __restrict__ b2,
    const float* __restrict__ lng, const float* __restrict__ lnb,
    float* __restrict__ out)
{
    __shared__ unsigned short sY[12][1032];   // 24.8 KB (row = 516 dwords)
    __shared__ unsigned short sZ[24][1032];   // 49.5 KB
    __shared__ float sMR[24][2];
    const int b = blockIdx.x;
    const int t = threadIdx.x;
    const int p0 = 2 * t;
    const size_t boff = (size_t)b * 12288;

    {
        const u32* gy = (const u32*)(y + boff);
#pragma unroll
        for (int ci = 0; ci < 12; ci++)
            ((u32*)&sY[ci][0])[t] = gy[ci * 512 + t];
    }
    const float lg0 = lng[p0], lb0 = lnb[p0];
    const float lg1 = lng[p0 + 1], lb1 = lnb[p0 + 1];
    const float lgm = (t > 0) ? lng[p0 - 1] : 0.f;
    const float lbm = (t > 0) ? lnb[p0 - 1] : 0.f;
    const float lgp = (t < 511) ? lng[p0 + 2] : 0.f;
    const float lbp = (t < 511) ? lnb[p0 + 2] : 0.f;
    __syncthreads();

    float2_t acc[12];
#pragma unroll
    for (int o = 0; o < 12; o++) { float bv = b2[o]; acc[o] = float2_t{bv, bv}; }

    for (int half = 0; half < 2; half++) {
        // conv1 (12 -> this half's 24 channels), ci-outer, acc in regs
        float2_t a1[24];
#pragma unroll
        for (int o = 0; o < 24; o++) {
            float bo = b1[half * 24 + o];
            a1[o] = float2_t{bo, bo};
        }
        for (int ci = 0; ci < 12; ci++) {
            u32 pr = *(const u32*)(&sY[ci][p0]);
            float2_t c = make2u(pr);                       // y[p0], y[p0+1]
            float ym = (t > 0) ? b2f(sY[ci][p0 - 1]) : 0.f;
            float yp = (t < 511) ? b2f(sY[ci][p0 + 2]) : 0.f;
            float2_t vm = float2_t{ym, c.x};
            float2_t vp = float2_t{c.y, yp};
            const float* wp = w1 + half * 24 * 36 + ci * 3;  // uniform -> SGPR
#pragma unroll
            for (int o = 0; o < 24; o++)
                a1[o] += vm * wp[o * 36] + c * wp[o * 36 + 1] + vp * wp[o * 36 + 2];
        }
#pragma unroll
        for (int o = 0; o < 24; o++) {
            u32 pz = ((u32)f2b(gelu_fast(a1[o].y)) << 16) | f2b(gelu_fast(a1[o].x));
            *(u32*)(&sZ[o][p0]) = pz;
        }
        __syncthreads();

        // LN stats over length: wave wv handles channels wv, wv+8, wv+16
        {
            const int wv = t >> 6, la = t & 63;
#pragma unroll
            for (int j = 0; j < 3; j++) {
                const int ch = wv + j * 8;
                float s = 0.f, ss = 0.f;
#pragma unroll
                for (int u = 0; u < 8; u++) {
                    float2_t v = make2u(((const u32*)&sZ[ch][0])[la + u * 64]);
                    s += v.x + v.y;
                    ss += v.x * v.x + v.y * v.y;
                }
#pragma unroll
                for (int off = 32; off >= 1; off >>= 1) {
                    s += __shfl_xor(s, off);
                    ss += __shfl_xor(ss, off);
                }
                if (la == 0) {
                    float mu = s * (1.f / 1024.f);
                    float var = ss * (1.f / 1024.f) - mu * mu;
                    sMR[ch][0] = mu;
                    sMR[ch][1] = rsqrtf(var + 1e-5f);
                }
            }
        }
        __syncthreads();

        // conv2 partial with LN folded into the tap reads
        for (int ci = 0; ci < 24; ci++) {
            const float mu = sMR[ci][0], rs = sMR[ci][1];
            u32 pr = *(const u32*)(&sZ[ci][p0]);
            float2_t c = make2u(pr);
            float zmr = (t > 0) ? b2f(sZ[ci][p0 - 1]) : 0.f;
            float zpr = (t < 511) ? b2f(sZ[ci][p0 + 2]) : 0.f;
            float2_t z0 = float2_t{(c.x - mu) * rs * lg0 + lb0,
                                   (c.y - mu) * rs * lg1 + lb1};
            float2_t zm = float2_t{(t > 0) ? ((zmr - mu) * rs * lgm + lbm) : 0.f,
                                   z0.x};
            float2_t zp = float2_t{z0.y,
                                   (t < 511) ? ((zpr - mu) * rs * lgp + lbp) : 0.f};
            const float* wp = w2 + (half * 24 + ci) * 3;   // uniform -> SGPR
#pragma unroll
            for (int o = 0; o < 12; o++)
                acc[o] += zm * wp[o * 144] + z0 * wp[o * 144 + 1] + zp * wp[o * 144 + 2];
        }
        __syncthreads();   // before next half overwrites sZ
    }

#pragma unroll
    for (int o = 0; o < 12; o++) {
        size_t i0 = boff + (size_t)o * 1024 + p0;
        float2_t sk = *(const float2_t*)(&skip[i0]);
        *(float2_t*)(&out[i0]) = acc[o] + sk;
    }
}

// ------------------------------ launcher -----------------------------------

extern "C" void kernel_launch(void* const* d_in, const int* in_sizes, int n_in,
                              void* d_out, int out_size, void* d_ws, size_t ws_size,
                              hipStream_t stream)
{
    (void)in_sizes; (void)n_in; (void)out_size; (void)ws_size;
    const float* x      = (const float*)d_in[0];
    const float* ln_g   = (const float*)d_in[1];
    const float* ln_b   = (const float*)d_in[2];
    const float* fc1_w  = (const float*)d_in[3];
    const float* fc1_b  = (const float*)d_in[4];
    const float* fc2_w  = (const float*)d_in[5];
    const float* fc2_b  = (const float*)d_in[6];
    const float* conv1_w= (const float*)d_in[7];
    const float* conv1_b= (const float*)d_in[8];
    const float* conv2_w= (const float*)d_in[9];
    const float* conv2_b= (const float*)d_in[10];
    const float* xl_g   = (const float*)d_in[11];
    const float* xl_b   = (const float*)d_in[12];
    const float* Wg     = (const float*)d_in[13];
    const float* bg     = (const float*)d_in[14];
    const float* Rg     = (const float*)d_in[15];
    const float* gn_g   = (const float*)d_in[16];
    const float* gn_b   = (const float*)d_in[17];
    const float* upl_w  = (const float*)d_in[18];
    const float* upl_b  = (const float*)d_in[19];
    const float* upr_w  = (const float*)d_in[20];
    const float* upr_b  = (const float*)d_in[21];
    const float* down_w = (const float*)d_in[22];
    const float* down_b = (const float*)d_in[23];

    char* ws = (char*)d_ws;
    size_t off = 0;
    auto alloc = [&](size_t bytes) -> char* {
        char* p = ws + off;
        off = (off + bytes + 255) & ~(size_t)255;
        return p;
    };
    float* xn            = (float*)alloc(25165824);          // 6144x1024 f32
    float* xc            = (float*)alloc(25165824);
    float* x1            = (float*)alloc(25165824);
    unsigned short* xn2b = (unsigned short*)alloc(12582912); // 6144x1024 bf16
    unsigned short* gxb  = (unsigned short*)alloc(50331648); // 6144x4096 bf16
    unsigned short* hnb  = (unsigned short*)alloc(12582912);
    unsigned short* glrb = (unsigned short*)alloc(12582912);
    unsigned short* yb   = (unsigned short*)alloc(12582912); // bf16 now
    unsigned short* WgT  = (unsigned short*)alloc(8388608);  // 4096x1024 bf16
    unsigned short* WupT = (unsigned short*)alloc(4194304);  // 2048x1024 bf16
    unsigned short* WdT  = (unsigned short*)alloc(2097152);  // 1024x1024 bf16

    // weight prep
    transpose_bf16_k<<<dim3(128, 32), 256, 0, stream>>>(Wg, WgT, 1024, 4096);
    transpose_bf16_k<<<dim3(32, 32), 256, 0, stream>>>(upl_w, WupT, 1024, 1024);
    transpose_bf16_k<<<dim3(32, 32), 256, 0, stream>>>(upr_w, WupT + 1024 * 1024, 1024, 1024);
    transpose_bf16_k<<<dim3(32, 32), 256, 0, stream>>>(down_w, WdT, 1024, 1024);

    // main pipeline
    ln_kernel<0><<<6144, 256, 0, stream>>>(x, ln_g, ln_b, xn);
    fc_kernel<<<2048, 256, 0, stream>>>(xn, fc1_w, fc1_b, fc2_w, fc2_b, xc, x1);
    ln_kernel<1><<<6144, 256, 0, stream>>>(x1, xl_g, xl_b, xn2b);
    gemm_kernel<0><<<dim3(32, 48), 256, 0, stream>>>(
        xn2b, WgT, bg, gxb, 6144, 4096, 1024, nullptr, nullptr, nullptr);
    slstm_rec_kernel<<<dim3(8, 32), 1024, 0, stream>>>(Rg, gxb, gn_g, gn_b, hnb);
    gemm_upgate_kernel<<<dim3(8, 48), 256, 0, stream>>>(
        hnb, WupT, upl_b, upr_b, glrb, 1024);
    gemm_kernel<2><<<dim3(8, 48), 256, 0, stream>>>(
        glrb, WdT, down_b, yb, 6144, 1024, 1024, xc, x1, xn);
    tail_fused_kernel<<<512, 512, 0, stream>>>(
        yb, xn, conv1_w, conv1_b, conv2_w, conv2_b, ln_g, ln_b, (float*)d_out);
}

// Round 8
// 466.706 us; speedup vs baseline: 1.1030x; 1.1030x over previous
//
#include <hip/hip_runtime.h>
#include <math.h>

// ---------------------------------------------------------------------------
// xLSTM decoder block, MI355X gfx950.
// Pipeline (all flat (b*12+ch)*1024+l layout):
//  prep:  weights -> bf16 (Wg/upl/upr/down transposed to [n][k])
//  ln1:   x -> xn (fp32)  [skip]
//  fc:    xn -> xc, x1 (fp32)
//  ln2:   x1 -> xn2 (bf16)
//  gemm0: xn2 @ WgT + bg -> gx (bf16, 6144x4096)
//  rec:   MFMA sLSTM per (head, 16 batches): R^T in VGPR B-fragments
//  gemm0: hn @ WupT -> lr (bf16, 6144x2048)    [Round-8: upgate fusion
//  gate:  glr = gelu(l)*r (vectorized, fast gelu)  reverted — it cost ~19us]
//  gemm2: glr @ WdT + down_b ; epilogue y = silu(xc)*(acc+b+x1)+xn -> yb bf16
//  tail:  FUSED conv1+gelu+LN(len)+conv2+skip. Round-8 v5: R6's o-outer
//         strided-pair structure, but 12-channel QUARTERS -> 49 KB LDS ->
//         3 blocks/CU (6 waves/SIMD, was 2 blocks at VALUBusy 57%).
//         launch_bounds(512,6); accumulator arrays capped at 12 (v4's 24-wide
//         ci-outer caused the R7 regression).
// ---------------------------------------------------------------------------

typedef short short8_t __attribute__((ext_vector_type(8)));
typedef float floatx4 __attribute__((ext_vector_type(4)));
typedef float float2_t __attribute__((ext_vector_type(2)));

typedef unsigned int u32;
typedef const __attribute__((address_space(1))) u32 gu32;
typedef __attribute__((address_space(3))) u32 lu32;

static __device__ __forceinline__ float b2f(unsigned short u) {
    unsigned v = ((unsigned)u) << 16;
    return __builtin_bit_cast(float, v);
}
static __device__ __forceinline__ unsigned short f2b(float f) {
    unsigned u = __builtin_bit_cast(unsigned, f);
    u += 0x7FFFu + ((u >> 16) & 1u);   // RNE
    return (unsigned short)(u >> 16);
}
static __device__ __forceinline__ float2_t make2u(unsigned u) {
    float2_t r;
    r.x = __builtin_bit_cast(float, u << 16);
    r.y = __builtin_bit_cast(float, u & 0xFFFF0000u);
    return r;
}
static __device__ __forceinline__ u32 pack2(float a, float b) {
    return ((u32)f2b(b) << 16) | (u32)f2b(a);
}
// tanh-form gelu; max abs err ~3e-3, negligible after 0.02-scale follow-on.
static __device__ __forceinline__ float gelu_fast(float x) {
    float u = 0.7978845608f * x * (1.f + 0.044715f * x * x);
    u = fminf(fmaxf(u, -9.f), 9.f);
    float e = __expf(2.f * u);
    float t = (e - 1.f) / (e + 1.f);
    return 0.5f * x * (1.f + t);
}

// --------------------------- weight prep ----------------------------------

__global__ __launch_bounds__(256) void transpose_bf16_k(
    const float* __restrict__ src, unsigned short* __restrict__ dst, int K, int N)
{   // dst[n*K+k] = bf16(src[k*N+n]); grid (N/32, K/32), block 256
    __shared__ unsigned short tl[32][33];
    const int n0 = blockIdx.x * 32, k0 = blockIdx.y * 32;
    const int tx = threadIdx.x & 31, ty = threadIdx.x >> 5;
#pragma unroll
    for (int r = 0; r < 4; r++) {
        int k = ty + r * 8;
        tl[tx][k] = f2b(src[(size_t)(k0 + k) * N + n0 + tx]);
    }
    __syncthreads();
#pragma unroll
    for (int r = 0; r < 4; r++) {
        int n = ty * 4 + r;
        dst[(size_t)(n0 + n) * K + k0 + tx] = tl[n][tx];
    }
}

// ------------------------------ layernorm ----------------------------------

template <int BF16OUT>
__global__ __launch_bounds__(256) void ln_kernel(
    const float* __restrict__ in, const float* __restrict__ g,
    const float* __restrict__ be, void* __restrict__ outp)
{
    const int row = blockIdx.x;
    const float* xr = in + (size_t)row * 1024;
    const int t = threadIdx.x;
    float v[4];
    float s = 0.f, ss = 0.f;
#pragma unroll
    for (int u = 0; u < 4; u++) {
        float q = xr[t + u * 256];
        v[u] = q; s += q; ss += q * q;
    }
#pragma unroll
    for (int off = 32; off >= 1; off >>= 1) {
        s += __shfl_xor(s, off);
        ss += __shfl_xor(ss, off);
    }
    __shared__ float red[8];
    const int wv = t >> 6, la = t & 63;
    if (la == 0) { red[wv] = s; red[4 + wv] = ss; }
    __syncthreads();
    s = red[0] + red[1] + red[2] + red[3];
    ss = red[4] + red[5] + red[6] + red[7];
    float mu = s * (1.f / 1024.f);
    float var = ss * (1.f / 1024.f) - mu * mu;
    float rs = rsqrtf(var + 1e-5f);
#pragma unroll
    for (int u = 0; u < 4; u++) {
        int i = t + u * 256;
        float yv = (v[u] - mu) * rs * g[i] + be[i];
        if (BF16OUT)
            ((unsigned short*)outp)[(size_t)row * 1024 + i] = f2b(yv);
        else
            ((float*)outp)[(size_t)row * 1024 + i] = yv;
    }
}

// ---------------------- fc1 (conv k3) + fc2 (1x1) --------------------------

__global__ __launch_bounds__(256) void fc_kernel(
    const float* __restrict__ xn,
    const float* __restrict__ w1, const float* __restrict__ b1,
    const float* __restrict__ w2, const float* __restrict__ b2,
    float* __restrict__ xc, float* __restrict__ x1)
{
    const int t = threadIdx.x;
    const int gid = blockIdx.x * 256 + t;
    const int b = gid >> 10, l = gid & 1023;
    const float* xb = xn + (size_t)b * 12288;
    float inm[12], in0[12], inp[12];
#pragma unroll
    for (int ci = 0; ci < 12; ci++) {
        in0[ci] = xb[ci * 1024 + l];
        inm[ci] = (l > 0) ? xb[ci * 1024 + l - 1] : 0.f;
        inp[ci] = (l < 1023) ? xb[ci * 1024 + l + 1] : 0.f;
    }
    float xcv[12];
#pragma unroll
    for (int o = 0; o < 12; o++) {
        float a = b1[o];
#pragma unroll
        for (int ci = 0; ci < 12; ci++) {
            const float* wp = w1 + o * 36 + ci * 3;  // uniform -> s_load
            a += inm[ci] * wp[0] + in0[ci] * wp[1] + inp[ci] * wp[2];
        }
        xcv[o] = a;
        xc[(size_t)b * 12288 + o * 1024 + l] = a;
    }
#pragma unroll
    for (int o = 0; o < 12; o++) {
        float a = b2[o];
#pragma unroll
        for (int ci = 0; ci < 12; ci++) a += xcv[ci] * w2[o * 12 + ci];
        x1[(size_t)b * 12288 + o * 1024 + l] = a;
    }
}

// ------------------------------ bf16 GEMM ----------------------------------
// MODE 0: store bf16.  MODE 2: y = silu(xc)*(acc+bias+x1) + skip, store bf16.

template <int MODE>
__global__ __launch_bounds__(256) void gemm_kernel(
    const unsigned short* __restrict__ A, const unsigned short* __restrict__ BT,
    const float* __restrict__ bias, void* __restrict__ out,
    int M, int N, int K,
    const float* __restrict__ xc, const float* __restrict__ x1,
    const float* __restrict__ skip)
{
    __shared__ __align__(16) unsigned short sA[128 * 32];
    __shared__ __align__(16) unsigned short sB[128 * 32];
    const int t = threadIdx.x;
    const int m0 = blockIdx.y * 128;
    const int n0 = blockIdx.x * 128;
    const int w = t >> 6;
    const int lane = t & 63;
    const int wr = (w >> 1) * 64;
    const int wc = (w & 1) * 64;
    const int lrow = lane & 15;
    const int quad = lane >> 4;
    const int row_l = t >> 2;
    const int cs = (t & 3) * 8;

    const unsigned short* gA0 = A + (size_t)(m0 + row_l) * K + cs;
    const unsigned short* gA1 = A + (size_t)(m0 + row_l + 64) * K + cs;
    const unsigned short* gB0 = BT + (size_t)(n0 + row_l) * K + cs;
    const unsigned short* gB1 = BT + (size_t)(n0 + row_l + 64) * K + cs;
    unsigned short* lA0 = sA + w * 512;
    unsigned short* lA1 = sA + 2048 + w * 512;
    unsigned short* lB0 = sB + w * 512;
    unsigned short* lB1 = sB + 2048 + w * 512;

    floatx4 acc[4][4];
#pragma unroll
    for (int i = 0; i < 4; i++)
#pragma unroll
        for (int j = 0; j < 4; j++) acc[i][j] = (floatx4)0.f;

    for (int k0 = 0; k0 < K; k0 += 32) {
        __syncthreads();
        __builtin_amdgcn_global_load_lds((gu32*)(gA0 + k0), (lu32*)lA0, 16, 0, 0);
        __builtin_amdgcn_global_load_lds((gu32*)(gA1 + k0), (lu32*)lA1, 16, 0, 0);
        __builtin_amdgcn_global_load_lds((gu32*)(gB0 + k0), (lu32*)lB0, 16, 0, 0);
        __builtin_amdgcn_global_load_lds((gu32*)(gB1 + k0), (lu32*)lB1, 16, 0, 0);
        __syncthreads();
        short8_t af[4], bfr[4];
#pragma unroll
        for (int i = 0; i < 4; i++) {
            af[i] = *(const short8_t*)(sA + (wr + i * 16 + lrow) * 32 + quad * 8);
            bfr[i] = *(const short8_t*)(sB + (wc + i * 16 + lrow) * 32 + quad * 8);
        }
#pragma unroll
        for (int i = 0; i < 4; i++)
#pragma unroll
            for (int j = 0; j < 4; j++)
                acc[i][j] = __builtin_amdgcn_mfma_f32_16x16x32_bf16(
                    af[i], bfr[j], acc[i][j], 0, 0, 0);
    }

#pragma unroll
    for (int i = 0; i < 4; i++) {
#pragma unroll
        for (int j = 0; j < 4; j++) {
#pragma unroll
            for (int r = 0; r < 4; r++) {
                const int gm = m0 + wr + i * 16 + quad * 4 + r;
                const int gn = n0 + wc + j * 16 + lrow;
                const size_t idx = (size_t)gm * N + gn;
                float v = acc[i][j][r] + bias[gn];
                if (MODE == 0) {
                    ((unsigned short*)out)[idx] = f2b(v);
                } else {
                    float xcv = xc[idx];
                    float sig = xcv / (1.f + __expf(-xcv));
                    ((unsigned short*)out)[idx] =
                        f2b(sig * (v + x1[idx]) + skip[idx]);
                }
            }
        }
    }
}

// ------------------- sLSTM recurrence + GroupNorm (MFMA) -------------------
// grid (NH=8, B/16=32) = 256 blocks (1/CU), block 1024 (16 waves, 4/SIMD).

#define RECP 516   // f32 row stride for sRec (2-way bank aliasing only)
#define HBP  136   // bf16 row stride for sHb

__global__ __launch_bounds__(1024, 4) void slstm_rec_kernel(
    const float* __restrict__ Rg,             // [8][512][128] f32
    const unsigned short* __restrict__ gxb,   // [B][12][4096] bf16
    const float* __restrict__ gn_g, const float* __restrict__ gn_b,
    unsigned short* __restrict__ hnb)         // [B][12][1024] bf16
{
    __shared__ __align__(16) float sRec[16 * RECP];
    __shared__ __align__(16) unsigned short sHb[16 * HBP];
    const int head = blockIdx.x;
    const int b0 = blockIdx.y * 16;
    const int t = threadIdx.x;
    const int w = t >> 6;
    const int lane = t & 63;
    const int quad = lane >> 4;
    const int l16 = lane & 15;

    short8_t Bf[2][4];
    {
        const float* Rh = Rg + (size_t)head * 65536;
#pragma unroll
        for (int jt = 0; jt < 2; jt++)
#pragma unroll
            for (int kk = 0; kk < 4; kk++) {
                const float* src =
                    Rh + (size_t)(w * 32 + jt * 16 + l16) * 128 + kk * 32 + quad * 8;
                short8_t v;
#pragma unroll
                for (int j = 0; j < 8; j++) v[j] = (short)f2b(src[j]);
                Bf[jt][kk] = v;
            }
    }

    for (int i = t; i < 16 * HBP; i += 1024) sHb[i] = 0;

    const int la = lane;
    float c0 = 0.f, n0s = 0.f, m0 = 0.f;
    float c1 = 0.f, n1s = 0.f, m1 = 0.f;
    const float gg0 = gn_g[head * 128 + la];
    const float gg1 = gn_g[head * 128 + la + 64];
    const float gb0 = gn_b[head * 128 + la];
    const float gb1 = gn_b[head * 128 + la + 64];

    __syncthreads();

    for (int step = 0; step < 12; step++) {
        const unsigned short* gp =
            gxb + ((size_t)(b0 + w) * 12 + step) * 4096 + head * 512;
        float gz0 = b2f(gp[la]),       gz1 = b2f(gp[64 + la]);
        float gi0 = b2f(gp[128 + la]), gi1 = b2f(gp[192 + la]);
        float gf0 = b2f(gp[256 + la]), gf1 = b2f(gp[320 + la]);
        float go0 = b2f(gp[384 + la]), go1 = b2f(gp[448 + la]);

        short8_t Af[4];
#pragma unroll
        for (int kk = 0; kk < 4; kk++)
            Af[kk] = *(const short8_t*)(sHb + l16 * HBP + kk * 32 + quad * 8);
        floatx4 D0 = (floatx4)0.f, D1 = (floatx4)0.f;
#pragma unroll
        for (int kk = 0; kk < 4; kk++) {
            D0 = __builtin_amdgcn_mfma_f32_16x16x32_bf16(Af[kk], Bf[0][kk], D0, 0, 0, 0);
            D1 = __builtin_amdgcn_mfma_f32_16x16x32_bf16(Af[kk], Bf[1][kk], D1, 0, 0, 0);
        }
#pragma unroll
        for (int r = 0; r < 4; r++) {
            sRec[(quad * 4 + r) * RECP + w * 32 + l16] = D0[r];
            sRec[(quad * 4 + r) * RECP + w * 32 + 16 + l16] = D1[r];
        }
        __syncthreads();

        const float* rr = sRec + w * RECP;
        float zp0 = gz0 + rr[la],       zp1 = gz1 + rr[64 + la];
        float ip0 = gi0 + rr[128 + la], ip1 = gi1 + rr[192 + la];
        float fp0 = gf0 + rr[256 + la], fp1 = gf1 + rr[320 + la];
        float op0 = go0 + rr[384 + la], op1 = go1 + rr[448 + la];

        float e20 = __expf(2.f * zp0), e21 = __expf(2.f * zp1);
        float z0 = (e20 - 1.f) / (e20 + 1.f), z1 = (e21 - 1.f) / (e21 + 1.f);
        float o0 = 1.f / (1.f + __expf(-op0)), o1 = 1.f / (1.f + __expf(-op1));
        float mn0 = fmaxf(fp0 + m0, ip0), mn1 = fmaxf(fp1 + m1, ip1);
        float ie0 = __expf(ip0 - mn0), ie1 = __expf(ip1 - mn1);
        float fe0 = __expf(fp0 + m0 - mn0), fe1 = __expf(fp1 + m1 - mn1);
        c0 = fe0 * c0 + ie0 * z0;  c1 = fe1 * c1 + ie1 * z1;
        n0s = fe0 * n0s + ie0;     n1s = fe1 * n1s + ie1;
        m0 = mn0;                  m1 = mn1;
        float h0 = o0 * (c0 / n0s), h1 = o1 * (c1 / n1s);

        float s = h0 + h1, ss = h0 * h0 + h1 * h1;
#pragma unroll
        for (int off = 32; off >= 1; off >>= 1) {
            s += __shfl_xor(s, off);
            ss += __shfl_xor(ss, off);
        }
        float mu = s * (1.f / 128.f);
        float var = ss * (1.f / 128.f) - mu * mu;
        float rs = rsqrtf(var + 1e-5f);
        size_t base = ((size_t)(b0 + w) * 12 + step) * 1024 + head * 128;
        hnb[base + la] = f2b((h0 - mu) * rs * gg0 + gb0);
        hnb[base + la + 64] = f2b((h1 - mu) * rs * gg1 + gb1);

        sHb[w * HBP + la] = f2b(h0);
        sHb[w * HBP + la + 64] = f2b(h1);
        __syncthreads();
    }
}

// ------------------------------ gate kernel --------------------------------
// 2 elements/thread via dword loads; grid 12288 x 256.

__global__ __launch_bounds__(256) void gate_kernel(
    const unsigned short* __restrict__ lr, unsigned short* __restrict__ glr)
{
    u32 pi = blockIdx.x * 256 + threadIdx.x;   // pair index, 6144*512 total
    u32 m = pi >> 9, c = pi & 511;
    const u32* row = (const u32*)(lr + (size_t)m * 2048);
    float2_t lf = make2u(row[c]);
    float2_t rt = make2u(row[512 + c]);
    ((u32*)glr)[pi] = pack2(gelu_fast(lf.x) * rt.x, gelu_fast(lf.y) * rt.y);
}

// ---------------- fused tail: conv1+gelu+LN(len)+conv2+skip ----------------
// grid 512 (one block per batch), block 512 (8 waves).
// Round-8 v5: 12-channel quarters -> sY 24.6 KB + sZ 24.6 KB = 49.3 KB LDS
// -> 3 blocks/CU (6 waves/SIMD, launch_bounds(512,6)). Thread owns strided
// positions (p, p+512) for conv; normalize pass uses dword mapping (2 adjacent
// positions) for single-b32 LDS ops. Accumulator arrays <= 12 wide.

__global__ __launch_bounds__(512, 6) void tail_fused_kernel(
    const unsigned short* __restrict__ y, const float* __restrict__ skip,
    const float* __restrict__ w1, const float* __restrict__ b1,
    const float* __restrict__ w2, const float* __restrict__ b2,
    const float* __restrict__ lng, const float* __restrict__ lnb,
    float* __restrict__ out)
{
    __shared__ unsigned short sY[12][1026];   // 24.6 KB
    __shared__ unsigned short sZ[12][1026];   // 24.6 KB
    __shared__ float sMR[12][2];
    const int b = blockIdx.x;
    const int t = threadIdx.x;
    const int p = t;                          // positions p, p+512
    const size_t boff = (size_t)b * 12288;

    {
        const u32* gy = (const u32*)(y + boff);
#pragma unroll
        for (int ci = 0; ci < 12; ci++)
            ((u32*)&sY[ci][0])[t] = gy[ci * 512 + t];
    }
    // LN gains for the dword-mapped normalize pass (positions 2t, 2t+1)
    const float lgA = lng[2 * t], lbA = lnb[2 * t];
    const float lgB = lng[2 * t + 1], lbB = lnb[2 * t + 1];
    __syncthreads();

    float2_t acc[12];
#pragma unroll
    for (int o = 0; o < 12; o++) { float bv = b2[o]; acc[o] = float2_t{bv, bv}; }

    for (int q = 0; q < 4; q++) {
        // ---- conv1: 12 in -> this quarter's 12 out channels, ci-outer
        float2_t a1[12];
#pragma unroll
        for (int o = 0; o < 12; o++) {
            float bo = b1[q * 12 + o];
            a1[o] = float2_t{bo, bo};
        }
        for (int ci = 0; ci < 12; ci++) {
            float2_t v0 = float2_t{b2f(sY[ci][p]), b2f(sY[ci][p + 512])};
            float2_t vm = float2_t{(p > 0) ? b2f(sY[ci][p - 1]) : 0.f,
                                   b2f(sY[ci][p + 511])};
            float2_t vp = float2_t{b2f(sY[ci][p + 1]),
                                   (p < 511) ? b2f(sY[ci][p + 513]) : 0.f};
            const float* wp = w1 + ci * 3;             // uniform -> SGPR
#pragma unroll
            for (int o = 0; o < 12; o++) {
                const float* wo = wp + (q * 12 + o) * 36;
                a1[o] += vm * wo[0] + v0 * wo[1] + vp * wo[2];
            }
        }
#pragma unroll
        for (int o = 0; o < 12; o++) {
            sZ[o][p] = f2b(gelu_fast(a1[o].x));
            sZ[o][p + 512] = f2b(gelu_fast(a1[o].y));
        }
        __syncthreads();

        // ---- LN stats: wave wv handles ch wv, and ch 8+wv for wv<4
        {
            const int wv = t >> 6, la = t & 63;
#pragma unroll
            for (int j = 0; j < 2; j++) {
                const int ch = wv + j * 8;
                if (ch < 12) {
                    float s = 0.f, ss = 0.f;
#pragma unroll
                    for (int u = 0; u < 8; u++) {
                        float2_t v = make2u(((const u32*)&sZ[ch][0])[la + u * 64]);
                        s += v.x + v.y;
                        ss += v.x * v.x + v.y * v.y;
                    }
#pragma unroll
                    for (int off = 32; off >= 1; off >>= 1) {
                        s += __shfl_xor(s, off);
                        ss += __shfl_xor(ss, off);
                    }
                    if (la == 0) {
                        float mu = s * (1.f / 1024.f);
                        float var = ss * (1.f / 1024.f) - mu * mu;
                        sMR[ch][0] = mu;
                        sMR[ch][1] = rsqrtf(var + 1e-5f);
                    }
                }
            }
        }
        __syncthreads();

        // ---- normalize in place (dword mapping: one b32 read+write per ch)
#pragma unroll
        for (int ch = 0; ch < 12; ch++) {
            const float mu = sMR[ch][0], rs = sMR[ch][1];
            float2_t f = make2u(((const u32*)&sZ[ch][0])[t]);
            f.x = (f.x - mu) * rs * lgA + lbA;
            f.y = (f.y - mu) * rs * lgB + lbB;
            ((u32*)&sZ[ch][0])[t] = pack2(f.x, f.y);
        }
        __syncthreads();

        // ---- conv2 partial over this quarter's 12 input channels
        for (int ci = 0; ci < 12; ci++) {
            float2_t z0 = float2_t{b2f(sZ[ci][p]), b2f(sZ[ci][p + 512])};
            float2_t zm = float2_t{(p > 0) ? b2f(sZ[ci][p - 1]) : 0.f,
                                   b2f(sZ[ci][p + 511])};
            float2_t zp = float2_t{b2f(sZ[ci][p + 1]),
                                   (p < 511) ? b2f(sZ[ci][p + 513]) : 0.f};
            const float* wp = w2 + (q * 12 + ci) * 3;  // uniform -> SGPR
#pragma unroll
            for (int o = 0; o < 12; o++)
                acc[o] += zm * wp[o * 144] + z0 * wp[o * 144 + 1]
                        + zp * wp[o * 144 + 2];
        }
        __syncthreads();   // before next quarter overwrites sZ
    }

#pragma unroll
    for (int o = 0; o < 12; o++) {
        size_t i0 = boff + (size_t)o * 1024 + p;
        out[i0] = acc[o].x + skip[i0];
        out[i0 + 512] = acc[o].y + skip[i0 + 512];
    }
}

// ------------------------------ launcher -----------------------------------

extern "C" void kernel_launch(void* const* d_in, const int* in_sizes, int n_in,
                              void* d_out, int out_size, void* d_ws, size_t ws_size,
                              hipStream_t stream)
{
    (void)in_sizes; (void)n_in; (void)out_size; (void)ws_size;
    const float* x      = (const float*)d_in[0];
    const float* ln_g   = (const float*)d_in[1];
    const float* ln_b   = (const float*)d_in[2];
    const float* fc1_w  = (const float*)d_in[3];
    const float* fc1_b  = (const float*)d_in[4];
    const float* fc2_w  = (const float*)d_in[5];
    const float* fc2_b  = (const float*)d_in[6];
    const float* conv1_w= (const float*)d_in[7];
    const float* conv1_b= (const float*)d_in[8];
    const float* conv2_w= (const float*)d_in[9];
    const float* conv2_b= (const float*)d_in[10];
    const float* xl_g   = (const float*)d_in[11];
    const float* xl_b   = (const float*)d_in[12];
    const float* Wg     = (const float*)d_in[13];
    const float* bg     = (const float*)d_in[14];
    const float* Rg     = (const float*)d_in[15];
    const float* gn_g   = (const float*)d_in[16];
    const float* gn_b   = (const float*)d_in[17];
    const float* upl_w  = (const float*)d_in[18];
    const float* upl_b  = (const float*)d_in[19];
    const float* upr_w  = (const float*)d_in[20];
    const float* upr_b  = (const float*)d_in[21];
    const float* down_w = (const float*)d_in[22];
    const float* down_b = (const float*)d_in[23];

    char* ws = (char*)d_ws;
    size_t off = 0;
    auto alloc = [&](size_t bytes) -> char* {
        char* p = ws + off;
        off = (off + bytes + 255) & ~(size_t)255;
        return p;
    };
    float* xn            = (float*)alloc(25165824);          // 6144x1024 f32
    float* xc            = (float*)alloc(25165824);
    float* x1            = (float*)alloc(25165824);
    unsigned short* xn2b = (unsigned short*)alloc(12582912); // 6144x1024 bf16
    unsigned short* gxb  = (unsigned short*)alloc(50331648); // 6144x4096 bf16
    unsigned short* hnb  = (unsigned short*)alloc(12582912);
    unsigned short* lrb  = (unsigned short*)alloc(25165824); // 6144x2048 bf16
    unsigned short* glrb = (unsigned short*)alloc(12582912);
    unsigned short* yb   = (unsigned short*)alloc(12582912); // 6144x1024 bf16
    unsigned short* WgT  = (unsigned short*)alloc(8388608);  // 4096x1024 bf16
    unsigned short* WupT = (unsigned short*)alloc(4194304);  // 2048x1024 bf16
    unsigned short* WdT  = (unsigned short*)alloc(2097152);  // 1024x1024 bf16
    float* bup           = (float*)alloc(8192);              // 2048 f32

    // weight prep
    transpose_bf16_k<<<dim3(128, 32), 256, 0, stream>>>(Wg, WgT, 1024, 4096);
    transpose_bf16_k<<<dim3(32, 32), 256, 0, stream>>>(upl_w, WupT, 1024, 1024);
    transpose_bf16_k<<<dim3(32, 32), 256, 0, stream>>>(upr_w, WupT + 1024 * 1024, 1024, 1024);
    transpose_bf16_k<<<dim3(32, 32), 256, 0, stream>>>(down_w, WdT, 1024, 1024);
    {   // bup = [upl_b | upr_b]
        hipMemcpyAsync(bup, upl_b, 4096, hipMemcpyDeviceToDevice, stream);
        hipMemcpyAsync(bup + 1024, upr_b, 4096, hipMemcpyDeviceToDevice, stream);
    }

    // main pipeline
    ln_kernel<0><<<6144, 256, 0, stream>>>(x, ln_g, ln_b, xn);
    fc_kernel<<<2048, 256, 0, stream>>>(xn, fc1_w, fc1_b, fc2_w, fc2_b, xc, x1);
    ln_kernel<1><<<6144, 256, 0, stream>>>(x1, xl_g, xl_b, xn2b);
    gemm_kernel<0><<<dim3(32, 48), 256, 0, stream>>>(
        xn2b, WgT, bg, gxb, 6144, 4096, 1024, nullptr, nullptr, nullptr);
    slstm_rec_kernel<<<dim3(8, 32), 1024, 0, stream>>>(Rg, gxb, gn_g, gn_b, hnb);
    gemm_kernel<0><<<dim3(16, 48), 256, 0, stream>>>(
        hnb, WupT, bup, lrb, 6144, 2048, 1024, nullptr, nullptr, nullptr);
    gate_kernel<<<12288, 256, 0, stream>>>(lrb, glrb);
    gemm_kernel<2><<<dim3(8, 48), 256, 0, stream>>>(
        glrb, WdT, down_b, yb, 6144, 1024, 1024, xc, x1, xn);
    tail_fused_kernel<<<512, 512, 0, stream>>>(
        yb, xn, conv1_w, conv1_b, conv2_w, conv2_b, ln_g, ln_b, (float*)d_out);
}